// Round 10
// baseline (577.253 us; speedup 1.0000x reference)
//
#include <hip/hip_runtime.h>
#include <hip/hip_bf16.h>

// native clang vector types — __builtin_nontemporal_store rejects
// HIP_vector_type wrappers.
typedef float nfloat4 __attribute__((ext_vector_type(4)));

// ---------------- Kernel A: pack (color[src]<<2)|color[dst] per g-edge ----
__global__ void __launch_bounds__(256)
pack_edge_colors_kernel(const int4* __restrict__ src_g4,
                        const int4* __restrict__ dst_g4,
                        const int* __restrict__ src_g,
                        const int* __restrict__ dst_g,
                        const int* __restrict__ h_nodes,
                        unsigned char* __restrict__ pc,
                        int eg) {
    const int n4 = eg >> 2;
    const int stride = gridDim.x * blockDim.x;
    for (int i = blockIdx.x * blockDim.x + threadIdx.x; i < n4; i += stride) {
        int4 s = src_g4[i];
        int4 d = dst_g4[i];
        unsigned int p =
            (unsigned int)((h_nodes[s.x] << 2) | h_nodes[d.x])
          | ((unsigned int)((h_nodes[s.y] << 2) | h_nodes[d.y]) << 8)
          | ((unsigned int)((h_nodes[s.z] << 2) | h_nodes[d.z]) << 16)
          | ((unsigned int)((h_nodes[s.w] << 2) | h_nodes[d.w]) << 24);
        __builtin_nontemporal_store(p, (unsigned int*)(pc + (i << 2)));
    }
    int t = blockIdx.x * blockDim.x + threadIdx.x;
    int e = (n4 << 2) + t;
    if (e < eg) {
        pc[e] = (unsigned char)((h_nodes[src_g[e]] << 2) | h_nodes[dst_g[e]]);
    }
}

// ---------------- Kernel B1: combo byte per h-edge (pure gather) ----------
// 4 rows/thread: int4 index loads, 8 independent byte gathers, uchar4 store.
__global__ void __launch_bounds__(256)
combo_kernel(const int4* __restrict__ src_h4,
             const int4* __restrict__ dst_h4,
             const int* __restrict__ src_h,
             const int* __restrict__ dst_h,
             const unsigned char* __restrict__ pc,
             unsigned char* __restrict__ combo,
             int eh) {
    const int n4 = eh >> 2;
    const int stride = gridDim.x * blockDim.x;
    const int tid = blockIdx.x * blockDim.x + threadIdx.x;

    for (int i = tid; i < n4; i += stride) {
        int4 s = src_h4[i];
        int4 d = dst_h4[i];
        unsigned int ps0 = pc[s.x], pd0 = pc[d.x];
        unsigned int ps1 = pc[s.y], pd1 = pc[d.y];
        unsigned int ps2 = pc[s.z], pd2 = pc[d.z];
        unsigned int ps3 = pc[s.w], pd3 = pc[d.w];
        unsigned int cw = 0;
        {
            int a = ps0 >> 2, b = ps0 & 3, c = pd0 & 3;
            cw |= (unsigned int)(((a == c) << 2) | ((a == b) << 1) | (b == c));
        }
        {
            int a = ps1 >> 2, b = ps1 & 3, c = pd1 & 3;
            cw |= (unsigned int)(((a == c) << 2) | ((a == b) << 1) | (b == c)) << 8;
        }
        {
            int a = ps2 >> 2, b = ps2 & 3, c = pd2 & 3;
            cw |= (unsigned int)(((a == c) << 2) | ((a == b) << 1) | (b == c)) << 16;
        }
        {
            int a = ps3 >> 2, b = ps3 & 3, c = pd3 & 3;
            cw |= (unsigned int)(((a == c) << 2) | ((a == b) << 1) | (b == c)) << 24;
        }
        __builtin_nontemporal_store(cw, (unsigned int*)(combo + (i << 2)));
    }
    int e = (n4 << 2) + tid;
    if (e < eh) {
        unsigned int ps = pc[src_h[e]], pd = pc[dst_h[e]];
        int a = ps >> 2, b = ps & 3, c = pd & 3;
        combo[e] = (unsigned char)(((a == c) << 2) | ((a == b) << 1) | (b == c));
    }
}

// ---------------- Kernel B2: pure output stream (no LDS, no barriers) -----
// thread j owns float4 slot j (and j + stride, ...). lane = tid&15 is
// loop-invariant -> six 16B embedding vectors preloaded in registers;
// per iter: 1 broadcast byte load, 3 selects + 2 float4 adds, 1 nt store.
__global__ void __launch_bounds__(256)
stream_out_kernel(const unsigned char* __restrict__ combo,
                  const float* __restrict__ e1,
                  const float* __restrict__ e2,
                  const float* __restrict__ e3,
                  nfloat4* __restrict__ out4,
                  long long total4) {            // eh * 16
    const int lane = threadIdx.x & 15;
    const nfloat4 e1a = ((const nfloat4*)e1)[lane];
    const nfloat4 e1b = ((const nfloat4*)e1)[16 + lane];
    const nfloat4 e2a = ((const nfloat4*)e2)[lane];
    const nfloat4 e2b = ((const nfloat4*)e2)[16 + lane];
    const nfloat4 e3a = ((const nfloat4*)e3)[lane];
    const nfloat4 e3b = ((const nfloat4*)e3)[16 + lane];

    const long long stride = (long long)gridDim.x * blockDim.x;
    for (long long j = (long long)blockIdx.x * blockDim.x + threadIdx.x;
         j < total4; j += stride) {
        unsigned int c = combo[j >> 4];
        nfloat4 v = (c & 4u ? e1b : e1a)
                  + (c & 2u ? e2b : e2a)
                  + (c & 1u ? e3b : e3a);
        __builtin_nontemporal_store(v, &out4[j]);
    }
}

extern "C" void kernel_launch(void* const* d_in, const int* in_sizes, int n_in,
                              void* d_out, int out_size, void* d_ws, size_t ws_size,
                              hipStream_t stream) {
    const int* h_nodes = (const int*)d_in[0];
    const int* src_g   = (const int*)d_in[1];
    const int* dst_g   = (const int*)d_in[2];
    const int* src_h   = (const int*)d_in[3];
    const int* dst_h   = (const int*)d_in[4];
    const float* e1_w  = (const float*)d_in[5];
    const float* e2_w  = (const float*)d_in[6];
    const float* e3_w  = (const float*)d_in[7];

    const int eg = in_sizes[1];   // E_G = 1,600,000
    const int eh = in_sizes[3];   // E_H = 2,000,000

    unsigned char* pc    = (unsigned char*)d_ws;              // eg bytes
    unsigned char* combo = (unsigned char*)d_ws + (1 << 21);  // eh bytes @ +2MB

    pack_edge_colors_kernel<<<1024, 256, 0, stream>>>(
        (const int4*)src_g, (const int4*)dst_g, src_g, dst_g, h_nodes, pc, eg);

    combo_kernel<<<2048, 256, 0, stream>>>(
        (const int4*)src_h, (const int4*)dst_h, src_h, dst_h, pc, combo, eh);

    const long long total4 = (long long)eh * 16;
    stream_out_kernel<<<2048, 256, 0, stream>>>(
        combo, e1_w, e2_w, e3_w, (nfloat4*)d_out, total4);
}

// Round 11
// 558.618 us; speedup vs baseline: 1.0334x; 1.0334x over previous
//
#include <hip/hip_runtime.h>
#include <hip/hip_bf16.h>

// native clang vector types — __builtin_nontemporal_store rejects
// HIP_vector_type wrappers (uchar4*/float4*).
typedef float nfloat4 __attribute__((ext_vector_type(4)));

// Kernel A: per g-edge, pack (color[src]<<2)|color[dst] into one byte.
// int4 index loads, 4-byte packed nontemporal store (4 edges/thread).
__global__ void __launch_bounds__(256)
pack_edge_colors_kernel(const int4* __restrict__ src_g4,
                        const int4* __restrict__ dst_g4,
                        const int* __restrict__ src_g,
                        const int* __restrict__ dst_g,
                        const int* __restrict__ h_nodes,
                        unsigned char* __restrict__ pc,
                        int eg) {
    const int n4 = eg >> 2;
    const int stride = gridDim.x * blockDim.x;
    for (int i = blockIdx.x * blockDim.x + threadIdx.x; i < n4; i += stride) {
        int4 s = src_g4[i];
        int4 d = dst_g4[i];
        unsigned int p =
            (unsigned int)((h_nodes[s.x] << 2) | h_nodes[d.x])
          | ((unsigned int)((h_nodes[s.y] << 2) | h_nodes[d.y]) << 8)
          | ((unsigned int)((h_nodes[s.z] << 2) | h_nodes[d.z]) << 16)
          | ((unsigned int)((h_nodes[s.w] << 2) | h_nodes[d.w]) << 24);
        __builtin_nontemporal_store(p, (unsigned int*)(pc + (i << 2)));
    }
    int t = blockIdx.x * blockDim.x + threadIdx.x;
    int e = (n4 << 2) + t;
    if (e < eg) {
        pc[e] = (unsigned char)((h_nodes[src_g[e]] << 2) | h_nodes[dst_g[e]]);
    }
}

// Kernel B: software-pipelined tiles.
//  - tile t+1's index loads + gathers issue before tile t's store drain;
//  - stores are nontemporal (evict-first);
//  - per tile: 2 coalesced dword loads + 2 byte gathers per row (1 thr/row),
//    then 4096 LDS-fed 16B stores (contiguous 64 KB).
#define TILE 256

__global__ void __launch_bounds__(256)
triplet_out_kernel(const int* __restrict__ src_h,
                   const int* __restrict__ dst_h,
                   const unsigned char* __restrict__ pc,
                   const float* __restrict__ e1,
                   const float* __restrict__ e2,
                   const float* __restrict__ e3,
                   float* __restrict__ out,
                   int eh) {
    __shared__ float table[8 * 64];        // 2 KB: all 8 possible output rows
    __shared__ unsigned char combo_s[TILE];

    const int tid = threadIdx.x;

    for (int i = tid; i < 8 * 64; i += blockDim.x) {
        int combo = i >> 6;                // hac*4 + hab*2 + hbc
        int f     = i & 63;
        table[i] = e1[((combo >> 2) & 1) * 64 + f]
                 + e2[((combo >> 1) & 1) * 64 + f]
                 + e3[( combo       & 1) * 64 + f];
    }

    const nfloat4* table4 = (const nfloat4*)table;
    nfloat4* out4 = (nfloat4*)out;
    const long long ntiles = ((long long)eh + TILE - 1) / TILE;

    // ---- prologue: combo for the first tile ----
    long long t = blockIdx.x;
    unsigned char my_combo = 0;
    if (t < ntiles) {
        long long row = t * TILE + tid;
        if (row < eh) {
            int s = src_h[row];
            int d = dst_h[row];
            unsigned int ps = pc[s];       // (a<<2)|b
            unsigned int pd = pc[d];       // (?<<2)|c
            int a = (int)(ps >> 2);
            int b = (int)(ps & 3u);
            int c = (int)(pd & 3u);
            my_combo = (unsigned char)(((a == c) << 2) | ((a == b) << 1) |
                                       (int)(b == c));
        }
    }
    __syncthreads();                       // table ready; combo_s free

    while (t < ntiles) {
        combo_s[tid] = my_combo;
        __syncthreads();                   // combo_s ready for this tile

        // issue next tile's loads NOW — latency hides under the store drain
        long long t_next = t + gridDim.x;
        if (t_next < ntiles) {
            long long row = t_next * TILE + tid;
            if (row < eh) {
                int s = src_h[row];
                int d = dst_h[row];
                unsigned int ps = pc[s];
                unsigned int pd = pc[d];
                int a = (int)(ps >> 2);
                int b = (int)(ps & 3u);
                int c = (int)(pd & 3u);
                my_combo = (unsigned char)(((a == c) << 2) | ((a == b) << 1) |
                                           (int)(b == c));
            }
        }

        // stream this tile's output (contiguous 64 KB, full cache lines)
        long long base = t * TILE;
        int nrows = (eh - base) < TILE ? (int)(eh - base) : TILE;
        int total4 = nrows << 4;           // nrows * 16 float4
        for (int j = tid; j < total4; j += blockDim.x) {
            nfloat4 v = table4[combo_s[j >> 4] * 16 + (j & 15)];
            __builtin_nontemporal_store(v, &out4[base * 16 + j]);
        }

        t = t_next;
        __syncthreads();                   // protect combo_s before overwrite
    }
}

extern "C" void kernel_launch(void* const* d_in, const int* in_sizes, int n_in,
                              void* d_out, int out_size, void* d_ws, size_t ws_size,
                              hipStream_t stream) {
    const int* h_nodes = (const int*)d_in[0];
    const int* src_g   = (const int*)d_in[1];
    const int* dst_g   = (const int*)d_in[2];
    const int* src_h   = (const int*)d_in[3];
    const int* dst_h   = (const int*)d_in[4];
    const float* e1_w  = (const float*)d_in[5];
    const float* e2_w  = (const float*)d_in[6];
    const float* e3_w  = (const float*)d_in[7];

    const int eg = in_sizes[1];   // E_G = 1,600,000
    const int eh = in_sizes[3];   // E_H = 2,000,000

    unsigned char* pc = (unsigned char*)d_ws;   // E_G bytes of scratch

    pack_edge_colors_kernel<<<1024, 256, 0, stream>>>(
        (const int4*)src_g, (const int4*)dst_g, src_g, dst_g, h_nodes, pc, eg);

    triplet_out_kernel<<<2048, 256, 0, stream>>>(src_h, dst_h, pc,
                                                 e1_w, e2_w, e3_w,
                                                 (float*)d_out, eh);
}